// Round 11
// baseline (373.929 us; speedup 1.0000x reference)
//
#include <hip/hip_runtime.h>
#include <hip/hip_bf16.h>

typedef unsigned short ushort_t;
typedef short bf16x8 __attribute__((ext_vector_type(8)));
typedef ushort_t u16x8 __attribute__((ext_vector_type(8)));
typedef float f32x4 __attribute__((ext_vector_type(4)));

#define DEV static __device__ __forceinline__

DEV float bf2f(ushort_t u) { unsigned v = ((unsigned)u) << 16; float f; __builtin_memcpy(&f, &v, 4); return f; }
DEV short f2bf(float x) { __hip_bfloat16 h = __float2bfloat16(x); short s; __builtin_memcpy(&s, &h, 2); return s; }
DEV float sigm(float x) { return 1.0f / (1.0f + __expf(-x)); }

DEV bf16x8 cvt8(float4 a0, float4 a1) {
    bf16x8 t;
    t[0] = f2bf(a0.x); t[1] = f2bf(a0.y); t[2] = f2bf(a0.z); t[3] = f2bf(a0.w);
    t[4] = f2bf(a1.x); t[5] = f2bf(a1.y); t[6] = f2bf(a1.z); t[7] = f2bf(a1.w);
    return t;
}
DEV bf16x8 ld8f(const float* __restrict__ p) {
    return cvt8(*reinterpret_cast<const float4*>(p), *reinterpret_cast<const float4*>(p + 4));
}

// ---------------- K0: fp32 -> bf16 for hidden, W1, Wv (one launch; 8 elems/thread)
__global__ void k_cvt(const float* __restrict__ h, const float* __restrict__ W1,
                      const float* __restrict__ Wv, ushort_t* __restrict__ Hb,
                      ushort_t* __restrict__ Wcat) {
    long i = (long)blockIdx.x * 256 + threadIdx.x;
    const float* src;
    ushort_t* dst;
    if (i < 1048576) { src = h + i * 8; dst = Hb + i * 8; }
    else if (i < 1056768) { long j = i - 1048576; src = W1 + j * 8; dst = Wcat + j * 8; }
    else { long j = i - 1056768; src = Wv + j * 8; dst = Wcat + 65536 + j * 8; }
    const float4* p = reinterpret_cast<const float4*>(src);
    *reinterpret_cast<bf16x8*>(dst) = cvt8(p[0], p[1]);
}

// ---------------- K1: Ff[8192][64] = Hb@W1^T (fp32), VbT[64][8192] = (Hb@Wv^T)^T bf16
// 24 loads batched per 256-k chunk; sched_barrier pins them before the MFMAs.
__global__ __launch_bounds__(256, 2) void k_fv(const ushort_t* __restrict__ Hb,
        const ushort_t* __restrict__ Wcat,
        float* __restrict__ Ff, ushort_t* __restrict__ VbT) {
    int m0 = blockIdx.x * 16;
    int wave = threadIdx.x >> 6, lane = threadIdx.x & 63;
    int l16 = lane & 15, quad = lane >> 4;
    int cb = (wave & 1) * 32;
    int brow_off = (wave < 2) ? 0 : 64;   // rows 0-63 = W1, 64-127 = Wv
    f32x4 acc[2] = {};
    const ushort_t* arow = Hb + (long)(m0 + l16) * 1024;
    const ushort_t* brow0 = Wcat + (long)(brow_off + cb + l16) * 1024;
    const ushort_t* brow1 = Wcat + (long)(brow_off + cb + 16 + l16) * 1024;
    for (int kc = 0; kc < 1024; kc += 256) {
        bf16x8 a4[8], b04[8], b14[8];
#pragma unroll
        for (int u = 0; u < 8; u++) {
            int ko = kc + u * 32 + quad * 8;
            a4[u] = *reinterpret_cast<const bf16x8*>(arow + ko);
            b04[u] = *reinterpret_cast<const bf16x8*>(brow0 + ko);
            b14[u] = *reinterpret_cast<const bf16x8*>(brow1 + ko);
        }
        __builtin_amdgcn_sched_barrier(0);
#pragma unroll
        for (int u = 0; u < 8; u++) {
            acc[0] = __builtin_amdgcn_mfma_f32_16x16x32_bf16(a4[u], b04[u], acc[0], 0, 0, 0);
            acc[1] = __builtin_amdgcn_mfma_f32_16x16x32_bf16(a4[u], b14[u], acc[1], 0, 0, 0);
        }
    }
    bool isV = (wave >= 2);
#pragma unroll
    for (int c = 0; c < 2; c++)
#pragma unroll
        for (int rr = 0; rr < 4; rr++) {
            int row = m0 + quad * 4 + rr;
            int col = cb + c * 16 + l16;
            float v = acc[c][rr];
            if (!isV) Ff[row * 64 + col] = v;
            else VbT[(long)col * 8192 + row] = (ushort_t)f2bf(v);
        }
}

// ---------------- K2: gelu -> features -> Q,K,charge0; zero received. 256 blocks x 32 rows.
__global__ __launch_bounds__(256) void k_feat(const float* __restrict__ Ff,
        const float* __restrict__ b1, const float* __restrict__ W2, const float* __restrict__ b2,
        const float* __restrict__ Wq, const float* __restrict__ Wk,
        const float* __restrict__ Wc, const float* __restrict__ bc,
        ushort_t* __restrict__ Qb, ushort_t* __restrict__ Kb,
        float* __restrict__ charge0, float* __restrict__ received) {
    __shared__ float w2L[28 * 65], wqL[64 * 29], wkL[64 * 29], wcL[28], b2L[28];
    __shared__ float fL[4][64], featL[4][28];
    int tid = threadIdx.x;
    for (int i = tid; i < 28 * 64; i += 256) w2L[(i >> 6) * 65 + (i & 63)] = W2[i];
    for (int i = tid; i < 64 * 28; i += 256) {
        int r = i / 28, c = i - r * 28;
        wqL[r * 29 + c] = Wq[i];
        wkL[r * 29 + c] = Wk[i];
    }
    if (tid < 28) { wcL[tid] = Wc[tid]; b2L[tid] = b2[tid]; }
    __syncthreads();
    int w = tid >> 6, lane = tid & 63;
    float b1v = b1[lane];
    float bcv = bc[0];
    for (int it = 0; it < 8; it++) {
        int row = blockIdx.x * 32 + it * 4 + w;
        float x = Ff[row * 64 + lane] + b1v;
        fL[w][lane] = 0.5f * x * (1.0f + erff(x * 0.70710678118654752f));
        __syncthreads();
        if (lane < 28) {
            float s = b2L[lane];
#pragma unroll
            for (int j = 0; j < 64; j++) s += fL[w][j] * w2L[lane * 65 + j];
            featL[w][lane] = sigm(s);
        }
        __syncthreads();
        float q = 0.f, k = 0.f;
#pragma unroll
        for (int i = 0; i < 28; i++) {
            float fv = featL[w][i];
            q += fv * wqL[lane * 29 + i];
            k += fv * wkL[lane * 29 + i];
        }
        Qb[row * 64 + lane] = (ushort_t)f2bf(q * 0.125f);  // fold 1/sqrt(64)
        Kb[row * 64 + lane] = (ushort_t)f2bf(k);
        if (lane == 0) {
            float c = bcv;
#pragma unroll
            for (int i = 0; i < 28; i++) c += featL[w][i] * wcL[i];
            charge0[row] = sigm(c);
            received[row] = 0.f;
        }
        __syncthreads();
    }
}

DEV void tri_decode(int r, int& ti, int& tj) {
    int t = (int)((sqrtf(8.f * (float)r + 1.f) - 1.f) * 0.5f);
    while ((t + 1) * (t + 2) / 2 <= r) t++;
    while (t * (t + 1) / 2 > r) t--;
    ti = t;
    tj = r - t * (t + 1) / 2;
}

// ---------------- K3: compat = (Q/8)·K, causal 128x128 tiles; K fully unrolled (20 loads hoisted)
__global__ __launch_bounds__(256, 2) void k_compat(const ushort_t* __restrict__ Qb,
                                                   const ushort_t* __restrict__ Kb,
                                                   ushort_t* __restrict__ compat) {
    int bid = blockIdx.x;
    int b = bid / 136, r = bid % 136, ti, tj;
    tri_decode(r, ti, tj);
    int wave = threadIdx.x >> 6, lane = threadIdx.x & 63;
    int l16 = lane & 15, quad = lane >> 4;
    int rbase = b * 2048 + ti * 128 + wave * 32;
    int cbase = b * 2048 + tj * 128;
    f32x4 acc[2][8] = {};
    bf16x8 af[2][2], bf[2][8];
#pragma unroll
    for (int kc = 0; kc < 2; kc++) {
        int ko = kc * 32 + quad * 8;
#pragma unroll
        for (int f = 0; f < 2; f++) af[kc][f] = *reinterpret_cast<const bf16x8*>(Qb + (long)(rbase + f * 16 + l16) * 64 + ko);
#pragma unroll
        for (int f = 0; f < 8; f++) bf[kc][f] = *reinterpret_cast<const bf16x8*>(Kb + (long)(cbase + f * 16 + l16) * 64 + ko);
    }
    __builtin_amdgcn_sched_barrier(0);
#pragma unroll
    for (int kc = 0; kc < 2; kc++)
#pragma unroll
        for (int i = 0; i < 2; i++)
#pragma unroll
            for (int j = 0; j < 8; j++)
                acc[i][j] = __builtin_amdgcn_mfma_f32_16x16x32_bf16(af[kc][i], bf[kc][j], acc[i][j], 0, 0, 0);
    int colt = tj * 128;
#pragma unroll
    for (int i = 0; i < 2; i++)
#pragma unroll
        for (int j = 0; j < 8; j++)
#pragma unroll
            for (int rr = 0; rr < 4; rr++) {
                long rowg = rbase + i * 16 + quad * 4 + rr;
                int col = colt + j * 16 + l16;
                compat[rowg * 2048 + col] = (ushort_t)f2bf(acc[i][j][rr]);
            }
}

// ---------------- pass A: Lrow[n] = sum_m<=n exp(compat*sigma).
// Block = 16 rows; wave = 512-col strip; ALL 40 loads hoisted before sched_barrier.
template <int T>
__global__ __launch_bounds__(256, 2) void k_rowstats(const ushort_t* __restrict__ compat,
        const float4* __restrict__ charges4, const float* __restrict__ stepp,
        float* __restrict__ Lrow) {
    __shared__ float lsum[4][16];
    int bid = blockIdx.x;
    int b = bid & 3, rt = 127 - (bid >> 2);   // big tiles first
    int w = threadIdx.x >> 6, lane = threadIdx.x & 63;
    int r0 = rt * 16;
    int colbase = b * 2048;
    int mb = w * 512 + lane * 8;
    float step = stepp[0];
    float S[16];
#pragma unroll
    for (int i = 0; i < 16; i++) S[i] = 0.f;
    if (mb <= r0 + 15) {
        const ushort_t* cbase = compat + (long)(colbase + r0) * 2048 + mb;
        u16x8 cv[16];
#pragma unroll
        for (int i = 0; i < 16; i++) cv[i] = *reinterpret_cast<const u16x8*>(cbase + (long)i * 2048);
        float chx[8] = {}, chy[8] = {}, chz[8] = {}, chw[8] = {};
        if (T > 0) {
#pragma unroll
            for (int j = 0; j < 8; j++) {
                float4 c = charges4[colbase + mb + j];
                chx[j] = c.x;
                if (T > 1) chy[j] = c.y;
                if (T > 2) chz[j] = c.z;
                if (T > 3) chw[j] = c.w;
            }
        }
        float rfx[16] = {}, rfy[16] = {}, rfz[16] = {}, rfw[16] = {};
        if (T > 0) {
#pragma unroll
            for (int i = 0; i < 16; i++) {
                float4 c4 = charges4[colbase + r0 + i];
                rfx[i] = step * c4.x;
                if (T > 1) rfy[i] = step * c4.y;
                if (T > 2) rfz[i] = step * c4.z;
                if (T > 3) rfw[i] = step * c4.w;
            }
        }
        __builtin_amdgcn_sched_barrier(0);
#pragma unroll
        for (int i = 0; i < 16; i++) {
            int n = r0 + i;
#pragma unroll
            for (int j = 0; j < 8; j++) {
                float sg = 1.f;
                if (T > 0) sg += rfx[i] * chx[j];
                if (T > 1) sg += rfy[i] * chy[j];
                if (T > 2) sg += rfz[i] * chz[j];
                if (T > 3) sg += rfw[i] * chw[j];
                float e = (mb + j <= n) ? __expf(bf2f(cv[i][j]) * sg) : 0.f;
                S[i] += e;
            }
        }
    }
#pragma unroll
    for (int off = 32; off > 0; off >>= 1) {
#pragma unroll
        for (int i = 0; i < 16; i++) S[i] += __shfl_down(S[i], off);
    }
    if (lane == 0) {
#pragma unroll
        for (int i = 0; i < 16; i++) lsum[w][i] = S[i];
    }
    __syncthreads();
    if (threadIdx.x < 16) {
        float s = lsum[0][threadIdx.x] + lsum[1][threadIdx.x] + lsum[2][threadIdx.x] + lsum[3][threadIdx.x];
        Lrow[colbase + r0 + threadIdx.x] = fmaxf(s, 1e-30f);
    }
}

// ---------------- pass B: received[m] += sum_n attn[n][m]. Full 128x128 tile per block;
// all 8 compat loads hoisted before sched_barrier; n-side staged in LDS.
template <int T>
__global__ __launch_bounds__(256, 2) void k_colsum(const ushort_t* __restrict__ compat,
        const float4* __restrict__ charges4, const float* __restrict__ stepp,
        const float* __restrict__ Lrow, float* __restrict__ received) {
    __shared__ float nLi[128], nvx[128], nvy[128], nvz[128], nvw[128];
    __shared__ float sums[16][136];
    int bid = blockIdx.x;
    int b = bid & 3, r = bid >> 2, ti, tj;
    tri_decode(r, ti, tj);
    int tid = threadIdx.x;
    float step = stepp[0];
    if (tid < 128) {
        int nid = b * 2048 + ti * 128 + tid;
        nLi[tid] = 1.0f / Lrow[nid];
        if (T > 0) {
            float4 cn = charges4[nid];
            nvx[tid] = step * cn.x;
            if (T > 1) nvy[tid] = step * cn.y;
            if (T > 2) nvz[tid] = step * cn.z;
            if (T > 3) nvw[tid] = step * cn.w;
        }
    }
    __syncthreads();
    int cg = tid & 15, ng = tid >> 4;
    int m0 = tj * 128 + cg * 8;
    const ushort_t* cbase = compat + (long)(b * 2048 + ti * 128) * 2048 + m0;
    u16x8 cv[8];
#pragma unroll
    for (int nb = 0; nb < 8; nb++)
        cv[nb] = *reinterpret_cast<const u16x8*>(cbase + (long)(nb * 16 + ng) * 2048);
    float cmx[8] = {}, cmy[8] = {}, cmz[8] = {}, cmw[8] = {};
    if (T > 0) {
#pragma unroll
        for (int j = 0; j < 8; j++) {
            float4 c = charges4[b * 2048 + m0 + j];
            cmx[j] = c.x;
            if (T > 1) cmy[j] = c.y;
            if (T > 2) cmz[j] = c.z;
            if (T > 3) cmw[j] = c.w;
        }
    }
    __builtin_amdgcn_sched_barrier(0);
    bool diag = (ti == tj);
    float acc[8] = {};
#pragma unroll
    for (int nb = 0; nb < 8; nb++) {
        int nloc = nb * 16 + ng;
        float Li = nLi[nloc];
        float ax = (T > 0) ? nvx[nloc] : 0.f;
        float ay = (T > 1) ? nvy[nloc] : 0.f;
        float az = (T > 2) ? nvz[nloc] : 0.f;
        float aw = (T > 3) ? nvw[nloc] : 0.f;
        int nglob = ti * 128 + nloc;
#pragma unroll
        for (int j = 0; j < 8; j++) {
            float sg = 1.f;
            if (T > 0) sg += ax * cmx[j];
            if (T > 1) sg += ay * cmy[j];
            if (T > 2) sg += az * cmz[j];
            if (T > 3) sg += aw * cmw[j];
            float p = __expf(bf2f(cv[nb][j]) * sg) * Li;
            if (!diag || m0 + j <= nglob) acc[j] += p;
        }
    }
#pragma unroll
    for (int j = 0; j < 8; j++) sums[ng][cg * 8 + j] = acc[j];
    __syncthreads();
    if (tid < 128) {
        float s = 0.f;
#pragma unroll
        for (int g = 0; g < 16; g++) s += sums[g][tid];
        atomicAdd(&received[b * 2048 + tj * 128 + tid], s);
    }
}

// ---------------- charge update t (writes charges4 component T-1; re-zeroes received)
template <int T>
__global__ void k_charge(float* __restrict__ received, const float* __restrict__ charge0,
                         float4* __restrict__ charges4, const float* __restrict__ decayp) {
    int i = blockIdx.x * 256 + threadIdx.x;
    if (i >= 8192) return;
    float decay = decayp[0];
    float rcv = received[i];
    float sg = 1.0f / (1.0f + __expf(1.0f - rcv));
    float prev = (T == 1) ? charge0[i] : ((const float*)&charges4[i])[T - 2];
    ((float*)&charges4[i])[T - 1] = prev * (1.f - decay * sg);
    received[i] = 0.f;
}

// ---------------- final attention + PV, self-normalizing; 2-stage load rotation
__global__ __launch_bounds__(256, 2) void k_pv(const ushort_t* __restrict__ compat,
        const float4* __restrict__ charges4, const float* __restrict__ stepp,
        const ushort_t* __restrict__ VbT, float* __restrict__ Oacc) {
    __shared__ float accL[3][64][17];
    __shared__ float ssL[4][16];
    int bid = blockIdx.x;
    int b = bid & 3, rtile = 127 - (bid >> 2);  // big tiles dispatched first
    int r0 = rtile * 16;
    int w = threadIdx.x >> 6, lane = threadIdx.x & 63;
    int l16 = lane & 15, quad = lane >> 4;
    int rowl = r0 + l16;
    int rid = b * 2048 + rowl;
    float step = stepp[0];
    float4 c4 = charges4[rid];
    float rx = step * c4.x, ry = step * c4.y, rz = step * c4.z, rw = step * c4.w;
    const ushort_t* crow = compat + (long)rid * 2048;
    f32x4 acc[4] = {};
    float Ss = 0.f;
    int colend = r0 + 16;
    int kc0 = w * 32;
    u16x8 cv_n = {};
    bf16x8 vf_n[4] = {};
    if (kc0 < colend) {
        int mk = kc0 + quad * 8;
        cv_n = *reinterpret_cast<const u16x8*>(crow + mk);
#pragma unroll
        for (int f = 0; f < 4; f++)
            vf_n[f] = *reinterpret_cast<const bf16x8*>(VbT + (long)(f * 16 + l16) * 8192 + b * 2048 + mk);
    }
    for (int kc = kc0; kc < colend; kc += 128) {
        int mk = kc + quad * 8;
        u16x8 cv = cv_n;
        bf16x8 vf[4];
#pragma unroll
        for (int f = 0; f < 4; f++) vf[f] = vf_n[f];
        int kn = kc + 128;
        if (kn < colend) {
            int mkn = kn + quad * 8;
            cv_n = *reinterpret_cast<const u16x8*>(crow + mkn);
#pragma unroll
            for (int f = 0; f < 4; f++)
                vf_n[f] = *reinterpret_cast<const bf16x8*>(VbT + (long)(f * 16 + l16) * 8192 + b * 2048 + mkn);
        }
        const float4* chp = charges4 + b * 2048 + mk;
        bf16x8 pf;
#pragma unroll
        for (int j = 0; j < 8; j++) {
            float4 ch = chp[j];
            float sg = 1.f + rx * ch.x + ry * ch.y + rz * ch.z + rw * ch.w;
            float p = (mk + j <= rowl) ? __expf(bf2f(cv[j]) * sg) : 0.f;
            Ss += p;
            pf[j] = f2bf(p);
        }
#pragma unroll
        for (int f = 0; f < 4; f++)
            acc[f] = __builtin_amdgcn_mfma_f32_16x16x32_bf16(pf, vf[f], acc[f], 0, 0, 0);
    }
    Ss += __shfl_xor(Ss, 16);
    Ss += __shfl_xor(Ss, 32);
    if (quad == 0) ssL[w][l16] = Ss;
    if (w > 0) {
#pragma unroll
        for (int f = 0; f < 4; f++)
#pragma unroll
            for (int rr = 0; rr < 4; rr++)
                accL[w - 1][lane][f * 4 + rr] = acc[f][rr];
    }
    __syncthreads();
    if (w == 0) {
#pragma unroll
        for (int f = 0; f < 4; f++)
#pragma unroll
            for (int rr = 0; rr < 4; rr++)
                acc[f][rr] += accL[0][lane][f * 4 + rr] + accL[1][lane][f * 4 + rr] + accL[2][lane][f * 4 + rr];
        float Sinv[4];
#pragma unroll
        for (int rr = 0; rr < 4; rr++) {
            int idx = quad * 4 + rr;
            float st = ssL[0][idx] + ssL[1][idx] + ssL[2][idx] + ssL[3][idx];
            Sinv[rr] = 1.f / fmaxf(st, 1e-30f);
        }
#pragma unroll
        for (int f = 0; f < 4; f++)
#pragma unroll
            for (int rr = 0; rr < 4; rr++) {
                int row = r0 + quad * 4 + rr;
                Oacc[(long)(b * 2048 + row) * 64 + f * 16 + l16] = acc[f][rr] * Sinv[rr];
            }
    }
}

// ---------------- out = (Oacc @ Wo^T) * 0.1, fp32 store
__global__ __launch_bounds__(256) void k_oproj(const float* __restrict__ Oacc,
                                               const float* __restrict__ Wo,
                                               float* __restrict__ out) {
    int mt = blockIdx.x & 63, nt = blockIdx.x >> 6;
    int wave = threadIdx.x >> 6, lane = threadIdx.x & 63;
    int wm = wave >> 1, wn = wave & 1;
    int l16 = lane & 15, quad = lane >> 4;
    int row0 = mt * 128 + wm * 64;
    int col0 = nt * 128 + wn * 64;
    f32x4 acc[4][4] = {};
#pragma unroll
    for (int kc = 0; kc < 64; kc += 32) {
        int ko = kc + quad * 8;
        bf16x8 af[4], bfm[4];
#pragma unroll
        for (int f = 0; f < 4; f++) af[f] = ld8f(Oacc + (long)(row0 + f * 16 + l16) * 64 + ko);
#pragma unroll
        for (int f = 0; f < 4; f++) bfm[f] = ld8f(Wo + (long)(col0 + f * 16 + l16) * 64 + ko);
#pragma unroll
        for (int i = 0; i < 4; i++)
#pragma unroll
            for (int j = 0; j < 4; j++)
                acc[i][j] = __builtin_amdgcn_mfma_f32_16x16x32_bf16(af[i], bfm[j], acc[i][j], 0, 0, 0);
    }
#pragma unroll
    for (int i = 0; i < 4; i++)
#pragma unroll
        for (int j = 0; j < 4; j++)
#pragma unroll
            for (int rr = 0; rr < 4; rr++) {
                long rowg = row0 + i * 16 + quad * 4 + rr;
                int colg = col0 + j * 16 + l16;
                out[rowg * 1024 + colg] = acc[i][j][rr] * 0.1f;
            }
}

extern "C" void kernel_launch(void* const* d_in, const int* in_sizes, int n_in,
                              void* d_out, int out_size, void* d_ws, size_t ws_size,
                              hipStream_t stream) {
    const float* hidden = (const float*)d_in[0];
    const float* W1 = (const float*)d_in[1];
    const float* b1 = (const float*)d_in[2];
    const float* W2 = (const float*)d_in[3];
    const float* b2 = (const float*)d_in[4];
    const float* Wq = (const float*)d_in[5];
    const float* Wk = (const float*)d_in[6];
    const float* Wc = (const float*)d_in[7];
    const float* bc = (const float*)d_in[8];
    const float* Wv = (const float*)d_in[9];
    const float* Wo = (const float*)d_in[10];
    const float* stepp = (const float*)d_in[11];
    const float* decayp = (const float*)d_in[12];

    char* ws = (char*)d_ws;
    size_t off = 0;
    auto alloc = [&](size_t bytes) {
        void* p = ws + off;
        off += (bytes + 255) & ~(size_t)255;
        return p;
    };
    ushort_t* compat = (ushort_t*)alloc(8192UL * 2048 * 2);  // 32 MiB bf16
    ushort_t* Hb = (ushort_t*)alloc(8192UL * 1024 * 2);      // 16 MiB bf16 hidden
    ushort_t* Wcat = (ushort_t*)alloc(128UL * 1024 * 2);     // W1;Wv bf16
    float* Ff = (float*)alloc(8192UL * 64 * 4);              // 2 MiB
    ushort_t* Qb = (ushort_t*)alloc(8192UL * 64 * 2);
    ushort_t* Kb = (ushort_t*)alloc(8192UL * 64 * 2);
    ushort_t* VbT = (ushort_t*)alloc(64UL * 8192 * 2);
    float* Oacc = (float*)alloc(8192UL * 64 * 4);
    float4* charges4 = (float4*)alloc(8192UL * 16);
    float* charge0 = (float*)alloc(8192UL * 4);
    float* Lrow = (float*)alloc(8192UL * 4);
    float* received = (float*)alloc(8192UL * 4);
    (void)ws_size; (void)in_sizes; (void)n_in; (void)out_size;

    k_cvt<<<4160, 256, 0, stream>>>(hidden, W1, Wv, Hb, Wcat);
    k_fv<<<512, 256, 0, stream>>>(Hb, Wcat, Ff, VbT);
    k_feat<<<256, 256, 0, stream>>>(Ff, b1, W2, b2, Wq, Wk, Wc, bc, Qb, Kb, charge0, received);
    k_compat<<<544, 256, 0, stream>>>(Qb, Kb, compat);

    k_rowstats<0><<<512, 256, 0, stream>>>(compat, charges4, stepp, Lrow);
    k_colsum<0><<<544, 256, 0, stream>>>(compat, charges4, stepp, Lrow, received);
    k_charge<1><<<32, 256, 0, stream>>>(received, charge0, charges4, decayp);

    k_rowstats<1><<<512, 256, 0, stream>>>(compat, charges4, stepp, Lrow);
    k_colsum<1><<<544, 256, 0, stream>>>(compat, charges4, stepp, Lrow, received);
    k_charge<2><<<32, 256, 0, stream>>>(received, charge0, charges4, decayp);

    k_rowstats<2><<<512, 256, 0, stream>>>(compat, charges4, stepp, Lrow);
    k_colsum<2><<<544, 256, 0, stream>>>(compat, charges4, stepp, Lrow, received);
    k_charge<3><<<32, 256, 0, stream>>>(received, charge0, charges4, decayp);

    k_rowstats<3><<<512, 256, 0, stream>>>(compat, charges4, stepp, Lrow);
    k_colsum<3><<<544, 256, 0, stream>>>(compat, charges4, stepp, Lrow, received);
    k_charge<4><<<32, 256, 0, stream>>>(received, charge0, charges4, decayp);

    k_pv<<<512, 256, 0, stream>>>(compat, charges4, stepp, VbT, Oacc);
    k_oproj<<<512, 256, 0, stream>>>(Oacc, Wo, (float*)d_out);
}